// Round 15
// baseline (716.866 us; speedup 1.0000x reference)
//
#include <hip/hip_runtime.h>
#include <cmath>

typedef short short8 __attribute__((ext_vector_type(8)));
typedef float f32x16 __attribute__((ext_vector_type(16)));

#define EPSF 1.1920929e-07f

// ---------------- LDS layout (bytes), total 137216 (M=64, 1 block/CU) --------
#define LDS_XA   0        // [64][16] ushort bf16 xA (dead after P1)
#define LDS_A1H  2048     // [64][264] ushort (dead after P2h)
#define LDS_A1W  35840    // [64][264] ushort (dead after P2w)
#define LDS_A2H  69632    // [64][264] ushort (read through P3)
#define LDS_A2W  103424   // [64][264] ushort (read through P3)
#define LDS_H32  2048     // overlay A1H head: [64][16] f32 h[.][32]
#define LDS_TOTAL 137216

// ---------------- packed weights (ushort offsets) in d_ws (R9 layout) --------
// Swapped-operand packing (R6-R13 verified): A-frag lane l holds A'[m=l&31][k=(l>>5)*8+e],
// A'[m][k] = W[kt*16+k][chan(m)]; D reg rr (half q=l>>5) = channel base + q*16 + rr.
#define OFF1H 0        // 8 tiles x 1 kt
#define OFF1W 4096
#define OFF2H 8192     // 8 ct x 16 kt
#define OFF2W 73728
#define OFF3W 139264   // 16 d x 16 kt (chan stride 32)
#define OFF3H 270336   // 16 d x 16 kt (chan stride 33, k=0..31)
#define OFFH32 401408  // 16 kt (16 valid ch: col = rr*33+32, q==0 only)
#define OFFB_BYTES 819200  // float area: hb3 repacked [16][32] + hb32[16]

__device__ __forceinline__ unsigned short f2bf(float f) {   // round-half-up (pack/P0)
  union { float f; unsigned u; } v; v.f = f;
  return (unsigned short)((v.u + 0x8000u) >> 16);
}
__device__ __forceinline__ float sp_eps(float v) {          // softplus + EPS
  return fmaxf(v, 0.f) + __logf(1.f + __expf(-fabsf(v))) + EPSF;
}
__device__ __forceinline__ int chanm(int m) {               // (rr,q) channel of A-row m
  return (((m >> 2) & 1) << 4) + (m & 3) + ((m >> 3) << 2);
}
__device__ __forceinline__ unsigned cvtpk(float lo, float hi) {
  unsigned r;
  asm("v_cvt_pk_bf16_f32 %0, %1, %2" : "=v"(r) : "v"(lo), "v"(hi));
  return r;
}

__global__ void pack_weights(const float* __restrict__ hW1, const float* __restrict__ wW1,
                             const float* __restrict__ hW2, const float* __restrict__ wW2,
                             const float* __restrict__ hW3, const float* __restrict__ wW3,
                             const float* __restrict__ hb3,
                             unsigned short* __restrict__ out) {
  int bid = blockIdx.x, l = threadIdx.x;
  if (bid == 800) {     // repack hb3 to stride-32 (aligned float4) + hb32 tail
    float* fb = (float*)((char*)out + OFFB_BYTES);
    for (int idx = l; idx < 528; idx += 64) {
      int d = idx / 33, j = idx - d * 33;
      if (j < 32) fb[d * 32 + j] = hb3[idx];
      else fb[512 + d] = hb3[idx];
    }
    return;
  }
  int m = l & 31;
  const float* W; unsigned short* dst; int tile, col, NC;
  if (bid < 8)        { W = hW1; dst = out + OFF1H;  tile = bid;       col = tile * 32 + chanm(m); NC = 256; }
  else if (bid < 16)  { W = wW1; dst = out + OFF1W;  tile = bid - 8;   col = tile * 32 + chanm(m); NC = 256; }
  else if (bid < 144) { W = hW2; dst = out + OFF2H;  tile = bid - 16;  col = (tile >> 4) * 32 + chanm(m); NC = 256; }
  else if (bid < 272) { W = wW2; dst = out + OFF2W;  tile = bid - 144; col = (tile >> 4) * 32 + chanm(m); NC = 256; }
  else if (bid < 528) { W = wW3; dst = out + OFF3W;  tile = bid - 272; col = (tile >> 4) * 32 + chanm(m); NC = 512; }
  else if (bid < 784) { W = hW3; dst = out + OFF3H;  tile = bid - 528; col = (tile >> 4) * 33 + chanm(m); NC = 528; }
  else {
    W = hW3; dst = out + OFFH32; tile = bid - 784;
    int qq = (m >> 2) & 1, rr = (m & 3) + ((m >> 3) << 2);
    col = qq ? -1 : rr * 33 + 32; NC = 528;
  }
  int kt = (bid < 16) ? 0 : (tile & 15);
  int K  = (bid < 16) ? 16 : 256;
  int k0 = kt * 16 + (l >> 5) * 8;
  short8 v;
  #pragma unroll
  for (int e = 0; e < 8; e++) {
    float f = (col >= 0 && (k0 + e) < K) ? W[(k0 + e) * NC + col] : 0.f;
    v[e] = (short)f2bf(f);
  }
  *(short8*)(dst + (tile * 64 + l) * 8) = v;
}

__device__ __forceinline__ f32x16 bias_init(const float* __restrict__ b) {
  const float4* bp = (const float4*)b;
  float4 b0 = bp[0], b1 = bp[1], b2 = bp[2], b3 = bp[3];
  f32x16 a;
  a[0] = b0.x;  a[1] = b0.y;  a[2] = b0.z;  a[3] = b0.w;
  a[4] = b1.x;  a[5] = b1.y;  a[6] = b1.z;  a[7] = b1.w;
  a[8] = b2.x;  a[9] = b2.y;  a[10] = b2.z; a[11] = b2.w;
  a[12] = b3.x; a[13] = b3.y; a[14] = b3.z; a[15] = b3.w;
  return a;
}

__device__ __forceinline__ void store_act16(unsigned short* dst, f32x16 a) {
  unsigned pk0 = cvtpk(fmaxf(a[0], 0.f),  fmaxf(a[1], 0.f));
  unsigned pk1 = cvtpk(fmaxf(a[2], 0.f),  fmaxf(a[3], 0.f));
  unsigned pk2 = cvtpk(fmaxf(a[4], 0.f),  fmaxf(a[5], 0.f));
  unsigned pk3 = cvtpk(fmaxf(a[6], 0.f),  fmaxf(a[7], 0.f));
  unsigned pk4 = cvtpk(fmaxf(a[8], 0.f),  fmaxf(a[9], 0.f));
  unsigned pk5 = cvtpk(fmaxf(a[10], 0.f), fmaxf(a[11], 0.f));
  unsigned pk6 = cvtpk(fmaxf(a[12], 0.f), fmaxf(a[13], 0.f));
  unsigned pk7 = cvtpk(fmaxf(a[14], 0.f), fmaxf(a[15], 0.f));
  uint4 p0 = {pk0, pk1, pk2, pk3}, p1 = {pk4, pk5, pk6, pk7};
  *(uint4*)dst = p0;
  *(uint4*)(dst + 8) = p1;
}

#define MFMA(A, B, C) __builtin_amdgcn_mfma_f32_32x32x16_bf16((A), (B), (C), 0, 0, 0)

// spline for one (row, d): pair = (l, l^32), half q owns bins q*16..q*16+15.
// R9-verified logic, f32 e/h throughout.
__device__ __forceinline__ void spline_store(f32x16 e, f32x16 hh, int d, int rowl, int q,
                                             const float* __restrict__ H32p,
                                             const float* __restrict__ x,
                                             float* __restrict__ y, int r0) {
  int grow = r0 + rowl;
  float se = 0.f;
  #pragma unroll
  for (int k = 0; k < 16; k++) se += e[k];
  float so = __shfl_xor(se, 32);
  float s = se + so;
  float h16o = __shfl_xor(hh[0], 32);            // partner's h[start]
  float hlast = q ? H32p[rowl * 16 + d] : h16o;  // h[32] for q1, h[16] for q0
  float xbv = x[grow * 32 + 2 * d + 1];
  float xbs = xbv * s;
  float bl0 = q ? so : 0.f;
  int fnd = (xbs >= bl0) ? 1 : 0;
  float bl = bl0, cl2 = 0.f, sxl = bl0, sew = e[0], shl = hh[0], shr = hh[1], scl2 = 0.f;
  #pragma unroll
  for (int k = 0; k < 16; k++) {
    float hk = hh[k];
    float hn = (k < 15) ? hh[k + 1] : hlast;
    bool c = (xbs >= bl);
    sxl  = c ? bl   : sxl;
    sew  = c ? e[k] : sew;
    shl  = c ? hk   : shl;
    shr  = c ? hn   : shr;
    scl2 = c ? cl2  : scl2;
    cl2 += (hk + hn) * e[k];
    bl  += e[k];
  }
  float cl2o = __shfl_xor(cl2, 32);
  float S2 = cl2 + cl2o;
  scl2 += q ? cl2o : 0.f;                        // globalize upper half's prefix
  int   o_fnd  = __shfl_xor(fnd, 32);
  float o_sxl  = __shfl_xor(sxl, 32);
  float o_sew  = __shfl_xor(sew, 32);
  float o_shl  = __shfl_xor(shl, 32);
  float o_shr  = __shfl_xor(shr, 32);
  float o_scl2 = __shfl_xor(scl2, 32);
  bool other = q ? (fnd == 0) : (o_fnd != 0);
  float gsxl  = other ? o_sxl  : sxl;
  float gsew  = other ? o_sew  : sew;
  float gshl  = other ? o_shl  : shl;
  float gshr  = other ? o_shr  : shr;
  float gscl2 = other ? o_scl2 : scl2;
  float alpha = (xbs - gsxl) / (gsew + EPSF);
  float yv = (gscl2 + (alpha * alpha * (gshr - gshl) + 2.f * alpha * gshl) * gsew) / S2;
  if (q == 0) y[grow * 32 + 2 * d + 1] = yv;
}

__global__ __launch_bounds__(1024, 1) void fused_kernel(
    const float* __restrict__ x,
    const float* __restrict__ hb1, const float* __restrict__ hb2,
    const float* __restrict__ wb1, const float* __restrict__ wb2,
    const float* __restrict__ wb3,
    const unsigned short* __restrict__ pw,
    float* __restrict__ y) {
  extern __shared__ char lds[];
  const int t = threadIdx.x;
  const int w = t >> 6, l = t & 63, q = l >> 5, r32 = l & 31;
  const int r0 = blockIdx.x * 64;

  unsigned short* XA  = (unsigned short*)(lds + LDS_XA);
  unsigned short* A1H = (unsigned short*)(lds + LDS_A1H);
  unsigned short* A1W = (unsigned short*)(lds + LDS_A1W);
  unsigned short* A2H = (unsigned short*)(lds + LDS_A2H);
  unsigned short* A2W = (unsigned short*)(lds + LDS_A2W);
  const float* pwf = (const float*)((const char*)pw + OFFB_BYTES);

  // ---- P0: load x, emit y even cols, stage xA bf16 [64][16] ----
  if (t < 512) {
    int row = t >> 3, c4 = t & 7;
    float4 v = *(const float4*)(x + (r0 + row) * 32 + c4 * 4);
    y[(r0 + row) * 32 + c4 * 4] = v.x;
    y[(r0 + row) * 32 + c4 * 4 + 2] = v.z;
    unsigned short* xa = XA + row * 16 + c4 * 2;
    xa[0] = f2bf(v.x); xa[1] = f2bf(v.z);
  }
  __syncthreads();

  const bool netH = (w >= 8);
  const int ct = w & 7;

  // ---- P1: L1, 16 waves = 2 nets x 8 ct, both row-tiles, packed b128 writes ----
  {
    const float* b1 = netH ? hb1 : wb1;
    unsigned short* A1n = netH ? A1H : A1W;
    short8 af = *(const short8*)(pw + (netH ? OFF1H : OFF1W) + (ct * 64 + l) * 8);
    #pragma unroll
    for (int rt = 0; rt < 2; rt++) {
      short8 bx = *(const short8*)(XA + (rt * 32 + r32) * 16 + q * 8);
      f32x16 acc = bias_init(b1 + ct * 32 + q * 16);
      acc = MFMA(af, bx, acc);
      store_act16(A1n + (rt * 32 + r32) * 264 + ct * 32 + q * 16, acc);
    }
  }
  __syncthreads();

  // ---- P2h: A1h -> A2H, 16 units (ct x rt) ----
  const int p2ct = w & 7, p2rt = w >> 3;
  {
    f32x16 acc = bias_init(hb2 + p2ct * 32 + q * 16);
    const unsigned short* aB = pw + OFF2H + (p2ct * 16 * 64 + l) * 8;
    const unsigned short* bB = A1H + (p2rt * 32 + r32) * 264 + q * 8;
    #pragma unroll
    for (int kt = 0; kt < 16; kt++)
      acc = MFMA(*(const short8*)(aB + kt * 512), *(const short8*)(bB + kt * 16), acc);
    store_act16(A2H + (p2rt * 32 + r32) * 264 + p2ct * 32 + q * 16, acc);
  }
  __syncthreads();

  // ---- P2w: A1w -> A2W; waves 0,1 additionally compute h[.][32] from A2H ----
  f32x16 a32;
  const bool do32 = (w < 2);
  if (do32) {
    #pragma unroll
    for (int rr = 0; rr < 16; rr++) a32[rr] = 0.f;
    const unsigned short* a32p = pw + OFFH32 + l * 8;
    const unsigned short* bH = A2H + (w * 32 + r32) * 264 + q * 8;
    #pragma unroll
    for (int kt = 0; kt < 16; kt++)
      a32 = MFMA(*(const short8*)(a32p + kt * 512), *(const short8*)(bH + kt * 16), a32);
  }
  {
    f32x16 acc = bias_init(wb2 + p2ct * 32 + q * 16);
    const unsigned short* aB = pw + OFF2W + (p2ct * 16 * 64 + l) * 8;
    const unsigned short* bB = A1W + (p2rt * 32 + r32) * 264 + q * 8;
    #pragma unroll
    for (int kt = 0; kt < 16; kt++)
      acc = MFMA(*(const short8*)(aB + kt * 512), *(const short8*)(bB + kt * 16), acc);
    store_act16(A2W + (p2rt * 32 + r32) * 264 + p2ct * 32 + q * 16, acc);
  }
  if (do32 && q == 0) {      // A1H dead: H32 overlays its head
    float* o = (float*)(lds + LDS_H32) + (w * 32 + r32) * 16;
    const float* hb32 = pwf + 512;
    #pragma unroll
    for (int g = 0; g < 4; g++) {
      float4 v;
      v.x = sp_eps(a32[4 * g + 0] + hb32[4 * g + 0]);
      v.y = sp_eps(a32[4 * g + 1] + hb32[4 * g + 1]);
      v.z = sp_eps(a32[4 * g + 2] + hb32[4 * g + 2]);
      v.w = sp_eps(a32[4 * g + 3] + hb32[4 * g + 3]);
      *(float4*)(o + 4 * g) = v;
    }
  }
  __syncthreads();

  // ---- P3 (BARRIER-FREE): wave w owns d = w; row-tiles sequential, e/h pure f32 ----
  const int d = w;
  const float* H32p = (const float*)(lds + LDS_H32);
  const unsigned short* bWt = pw + OFF3W + (d * 16 * 64 + l) * 8;
  const unsigned short* bHt = pw + OFF3H + (d * 16 * 64 + l) * 8;

  #pragma unroll 1
  for (int rt = 0; rt < 2; rt++) {
    const unsigned short* baw = A2W + (rt * 32 + r32) * 264 + q * 8;
    const unsigned short* bah = A2H + (rt * 32 + r32) * 264 + q * 8;

    f32x16 e = bias_init(wb3 + d * 32 + q * 16);
    #pragma unroll
    for (int kt = 0; kt < 16; kt++)
      e = MFMA(*(const short8*)(bWt + kt * 512), *(const short8*)(baw + kt * 16), e);
    #pragma unroll
    for (int rr = 0; rr < 16; rr++) e[rr] = __expf(e[rr]);

    f32x16 hh = bias_init(pwf + d * 32 + q * 16);
    #pragma unroll
    for (int kt = 0; kt < 16; kt++)
      hh = MFMA(*(const short8*)(bHt + kt * 512), *(const short8*)(bah + kt * 16), hh);
    #pragma unroll
    for (int rr = 0; rr < 16; rr++) hh[rr] = sp_eps(hh[rr]);

    spline_store(e, hh, d, rt * 32 + r32, q, H32p, x, y, r0);
  }
}

extern "C" void kernel_launch(void* const* d_in, const int* in_sizes, int n_in,
                              void* d_out, int out_size, void* d_ws, size_t ws_size,
                              hipStream_t stream) {
  const float* x   = (const float*)d_in[0];
  const float* hW1 = (const float*)d_in[1];
  const float* hb1 = (const float*)d_in[2];
  const float* hW2 = (const float*)d_in[3];
  const float* hb2 = (const float*)d_in[4];
  const float* hW3 = (const float*)d_in[5];
  const float* hb3 = (const float*)d_in[6];
  const float* wW1 = (const float*)d_in[7];
  const float* wb1 = (const float*)d_in[8];
  const float* wW2 = (const float*)d_in[9];
  const float* wb2 = (const float*)d_in[10];
  const float* wW3 = (const float*)d_in[11];
  const float* wb3 = (const float*)d_in[12];
  unsigned short* pw = (unsigned short*)d_ws;

  pack_weights<<<801, 64, 0, stream>>>(hW1, wW1, hW2, wW2, hW3, wW3, hb3, pw);

  hipFuncSetAttribute((const void*)fused_kernel,
                      hipFuncAttributeMaxDynamicSharedMemorySize, LDS_TOTAL);
  fused_kernel<<<2048, 1024, LDS_TOTAL, stream>>>(
      x, hb1, hb2, wb1, wb2, wb3, pw, (float*)d_out);
}

// Round 16
// 208.870 us; speedup vs baseline: 3.4321x; 3.4321x over previous
//
#include <hip/hip_runtime.h>
#include <cmath>

typedef short short8 __attribute__((ext_vector_type(8)));
typedef float f32x16 __attribute__((ext_vector_type(16)));

#define EPSF 1.1920929e-07f

// ---------------- LDS layout (bytes), total 69632 -> 2 blocks/CU ----------------
#define LDS_XA   0        // [32][16] ushort bf16 xA (2048-B slot; dead after P1)
#define LDS_A1W  2048     // [32][264] ushort (dead after P2)
#define LDS_A1H  18944    // [32][264] ushort (dead after P2)
#define LDS_A2W  35840    // [32][264] ushort (read through P3)
#define LDS_A2H  52736    // [32][264] ushort (read through P3)
#define LDS_H32  0        // overlay XA slot: [32][16] f32 h[.][32] (2048 B)
#define LDS_TOTAL 69632

// ---------------- packed weights (ushort offsets) in d_ws (R9 layout) --------
// Swapped-operand packing (R6-R15 verified): A-frag lane l holds A'[m=l&31][k=(l>>5)*8+e],
// A'[m][k] = W[kt*16+k][chan(m)]; D reg rr (half q=l>>5) = channel base + q*16 + rr.
#define OFF1H 0        // 8 tiles x 1 kt
#define OFF1W 4096
#define OFF2H 8192     // 8 ct x 16 kt
#define OFF2W 73728
#define OFF3W 139264   // 16 d x 16 kt (chan stride 32)
#define OFF3H 270336   // 16 d x 16 kt (chan stride 33, k=0..31)
#define OFFH32 401408  // 16 kt (16 valid ch: col = rr*33+32, q==0 only)
#define OFFB_BYTES 819200  // float area: hb3 repacked [16][32] + hb32[16]

__device__ __forceinline__ unsigned short f2bf(float f) {   // round-half-up (pack/P0)
  union { float f; unsigned u; } v; v.f = f;
  return (unsigned short)((v.u + 0x8000u) >> 16);
}
__device__ __forceinline__ float sp_eps(float v) {          // softplus + EPS
  return fmaxf(v, 0.f) + __logf(1.f + __expf(-fabsf(v))) + EPSF;
}
__device__ __forceinline__ int chanm(int m) {               // (rr,q) channel of A-row m
  return (((m >> 2) & 1) << 4) + (m & 3) + ((m >> 3) << 2);
}
__device__ __forceinline__ unsigned cvtpk(float lo, float hi) {
  unsigned r;
  asm("v_cvt_pk_bf16_f32 %0, %1, %2" : "=v"(r) : "v"(lo), "v"(hi));
  return r;
}

__global__ void pack_weights(const float* __restrict__ hW1, const float* __restrict__ wW1,
                             const float* __restrict__ hW2, const float* __restrict__ wW2,
                             const float* __restrict__ hW3, const float* __restrict__ wW3,
                             const float* __restrict__ hb3,
                             unsigned short* __restrict__ out) {
  int bid = blockIdx.x, l = threadIdx.x;
  if (bid == 800) {     // repack hb3 to stride-32 (aligned float4) + hb32 tail
    float* fb = (float*)((char*)out + OFFB_BYTES);
    for (int idx = l; idx < 528; idx += 64) {
      int d = idx / 33, j = idx - d * 33;
      if (j < 32) fb[d * 32 + j] = hb3[idx];
      else fb[512 + d] = hb3[idx];
    }
    return;
  }
  int m = l & 31;
  const float* W; unsigned short* dst; int tile, col, NC;
  if (bid < 8)        { W = hW1; dst = out + OFF1H;  tile = bid;       col = tile * 32 + chanm(m); NC = 256; }
  else if (bid < 16)  { W = wW1; dst = out + OFF1W;  tile = bid - 8;   col = tile * 32 + chanm(m); NC = 256; }
  else if (bid < 144) { W = hW2; dst = out + OFF2H;  tile = bid - 16;  col = (tile >> 4) * 32 + chanm(m); NC = 256; }
  else if (bid < 272) { W = wW2; dst = out + OFF2W;  tile = bid - 144; col = (tile >> 4) * 32 + chanm(m); NC = 256; }
  else if (bid < 528) { W = wW3; dst = out + OFF3W;  tile = bid - 272; col = (tile >> 4) * 32 + chanm(m); NC = 512; }
  else if (bid < 784) { W = hW3; dst = out + OFF3H;  tile = bid - 528; col = (tile >> 4) * 33 + chanm(m); NC = 528; }
  else {
    W = hW3; dst = out + OFFH32; tile = bid - 784;
    int qq = (m >> 2) & 1, rr = (m & 3) + ((m >> 3) << 2);
    col = qq ? -1 : rr * 33 + 32; NC = 528;
  }
  int kt = (bid < 16) ? 0 : (tile & 15);
  int K  = (bid < 16) ? 16 : 256;
  int k0 = kt * 16 + (l >> 5) * 8;
  short8 v;
  #pragma unroll
  for (int e = 0; e < 8; e++) {
    float f = (col >= 0 && (k0 + e) < K) ? W[(k0 + e) * NC + col] : 0.f;
    v[e] = (short)f2bf(f);
  }
  *(short8*)(dst + (tile * 64 + l) * 8) = v;
}

__device__ __forceinline__ f32x16 bias_init(const float* __restrict__ b) {
  const float4* bp = (const float4*)b;
  float4 b0 = bp[0], b1 = bp[1], b2 = bp[2], b3 = bp[3];
  f32x16 a;
  a[0] = b0.x;  a[1] = b0.y;  a[2] = b0.z;  a[3] = b0.w;
  a[4] = b1.x;  a[5] = b1.y;  a[6] = b1.z;  a[7] = b1.w;
  a[8] = b2.x;  a[9] = b2.y;  a[10] = b2.z; a[11] = b2.w;
  a[12] = b3.x; a[13] = b3.y; a[14] = b3.z; a[15] = b3.w;
  return a;
}

__device__ __forceinline__ void store_act16(unsigned short* dst, f32x16 a) {
  unsigned pk0 = cvtpk(fmaxf(a[0], 0.f),  fmaxf(a[1], 0.f));
  unsigned pk1 = cvtpk(fmaxf(a[2], 0.f),  fmaxf(a[3], 0.f));
  unsigned pk2 = cvtpk(fmaxf(a[4], 0.f),  fmaxf(a[5], 0.f));
  unsigned pk3 = cvtpk(fmaxf(a[6], 0.f),  fmaxf(a[7], 0.f));
  unsigned pk4 = cvtpk(fmaxf(a[8], 0.f),  fmaxf(a[9], 0.f));
  unsigned pk5 = cvtpk(fmaxf(a[10], 0.f), fmaxf(a[11], 0.f));
  unsigned pk6 = cvtpk(fmaxf(a[12], 0.f), fmaxf(a[13], 0.f));
  unsigned pk7 = cvtpk(fmaxf(a[14], 0.f), fmaxf(a[15], 0.f));
  uint4 p0 = {pk0, pk1, pk2, pk3}, p1 = {pk4, pk5, pk6, pk7};
  *(uint4*)dst = p0;
  *(uint4*)(dst + 8) = p1;
}

#define MFMA(A, B, C) __builtin_amdgcn_mfma_f32_32x32x16_bf16((A), (B), (C), 0, 0, 0)

// spline for one (row, d): pair = (l, l^32), half q owns bins q*16..q*16+15.
// R9/R15-verified logic, f32 e/h throughout.
__device__ __forceinline__ void spline_store(f32x16 e, f32x16 hh, int d, int rowl, int q,
                                             const float* __restrict__ H32p,
                                             const float* __restrict__ x,
                                             float* __restrict__ y, int r0) {
  int grow = r0 + rowl;
  float se = 0.f;
  #pragma unroll
  for (int k = 0; k < 16; k++) se += e[k];
  float so = __shfl_xor(se, 32);
  float s = se + so;
  float h16o = __shfl_xor(hh[0], 32);            // partner's h[start]
  float hlast = q ? H32p[rowl * 16 + d] : h16o;  // h[32] for q1, h[16] for q0
  float xbv = x[grow * 32 + 2 * d + 1];
  float xbs = xbv * s;
  float bl0 = q ? so : 0.f;
  int fnd = (xbs >= bl0) ? 1 : 0;
  float bl = bl0, cl2 = 0.f, sxl = bl0, sew = e[0], shl = hh[0], shr = hh[1], scl2 = 0.f;
  #pragma unroll
  for (int k = 0; k < 16; k++) {
    float hk = hh[k];
    float hn = (k < 15) ? hh[k + 1] : hlast;
    bool c = (xbs >= bl);
    sxl  = c ? bl   : sxl;
    sew  = c ? e[k] : sew;
    shl  = c ? hk   : shl;
    shr  = c ? hn   : shr;
    scl2 = c ? cl2  : scl2;
    cl2 += (hk + hn) * e[k];
    bl  += e[k];
  }
  float cl2o = __shfl_xor(cl2, 32);
  float S2 = cl2 + cl2o;
  scl2 += q ? cl2o : 0.f;                        // globalize upper half's prefix
  int   o_fnd  = __shfl_xor(fnd, 32);
  float o_sxl  = __shfl_xor(sxl, 32);
  float o_sew  = __shfl_xor(sew, 32);
  float o_shl  = __shfl_xor(shl, 32);
  float o_shr  = __shfl_xor(shr, 32);
  float o_scl2 = __shfl_xor(scl2, 32);
  bool other = q ? (fnd == 0) : (o_fnd != 0);
  float gsxl  = other ? o_sxl  : sxl;
  float gsew  = other ? o_sew  : sew;
  float gshl  = other ? o_shl  : shl;
  float gshr  = other ? o_shr  : shr;
  float gscl2 = other ? o_scl2 : scl2;
  float alpha = (xbs - gsxl) / (gsew + EPSF);
  float yv = (gscl2 + (alpha * alpha * (gshr - gshl) + 2.f * alpha * gshl) * gsew) / S2;
  if (q == 0) y[grow * 32 + 2 * d + 1] = yv;
}

// 512-thread blocks escape the 64-VGPR allocator cap (R7: (512,2) -> 92 VGPR,
// no spill). (512,2): 2 blocks x 8 waves = 16 waves/CU -> VGPR cap 128.
__global__ __launch_bounds__(512, 2) void fused_kernel(
    const float* __restrict__ x,
    const float* __restrict__ hb1, const float* __restrict__ hb2,
    const float* __restrict__ wb1, const float* __restrict__ wb2,
    const float* __restrict__ wb3,
    const unsigned short* __restrict__ pw,
    float* __restrict__ y) {
  extern __shared__ char lds[];
  const int t = threadIdx.x;
  const int w = t >> 6, l = t & 63, q = l >> 5, r32 = l & 31;
  const int r0 = blockIdx.x * 32;

  unsigned short* XA  = (unsigned short*)(lds + LDS_XA);
  unsigned short* A1W = (unsigned short*)(lds + LDS_A1W);
  unsigned short* A1H = (unsigned short*)(lds + LDS_A1H);
  unsigned short* A2W = (unsigned short*)(lds + LDS_A2W);
  unsigned short* A2H = (unsigned short*)(lds + LDS_A2H);
  const float* pwf = (const float*)((const char*)pw + OFFB_BYTES);

  // ---- P0: load x, emit y even cols, stage xA bf16 [32][16] ----
  if (t < 256) {
    int row = t >> 3, c4 = t & 7;
    float4 v = *(const float4*)(x + (r0 + row) * 32 + c4 * 4);
    y[(r0 + row) * 32 + c4 * 4] = v.x;
    y[(r0 + row) * 32 + c4 * 4 + 2] = v.z;
    unsigned short* xa = XA + row * 16 + c4 * 2;
    xa[0] = f2bf(v.x); xa[1] = f2bf(v.z);
  }
  __syncthreads();

  const bool isH = (w >= 4);               // waves 0-3: w-net, 4-7: h-net
  const int ctp = (w & 3) * 2;             // each wave owns 2 col-tiles
  unsigned short* A1n = isH ? A1H : A1W;
  unsigned short* A2n = isH ? A2H : A2W;
  const float* b1 = isH ? hb1 : wb1;
  const float* b2 = isH ? hb2 : wb2;
  const int off1 = isH ? OFF1H : OFF1W;
  const int off2 = isH ? OFF2H : OFF2W;

  // ---- P1: L1 both nets parallel; one XA read shared by 2 MFMAs ----
  {
    short8 bx = *(const short8*)(XA + r32 * 16 + q * 8);
    #pragma unroll
    for (int u = 0; u < 2; u++) {
      int ct = ctp + u;
      f32x16 acc = bias_init(b1 + ct * 32 + q * 16);
      short8 af = *(const short8*)(pw + off1 + (ct * 64 + l) * 8);
      acc = MFMA(af, bx, acc);
      store_act16(A1n + r32 * 264 + ct * 32 + q * 16, acc);
    }
  }
  __syncthreads();

  // ---- P2: L2 both nets in ONE phase; each A1 read feeds 2 MFMAs ----
  {
    f32x16 acc0 = bias_init(b2 + ctp * 32 + q * 16);
    f32x16 acc1 = bias_init(b2 + (ctp + 1) * 32 + q * 16);
    const unsigned short* aB0 = pw + off2 + (ctp * 16 * 64 + l) * 8;
    const unsigned short* aB1 = pw + off2 + ((ctp + 1) * 16 * 64 + l) * 8;
    const unsigned short* bB = A1n + r32 * 264 + q * 8;
    #pragma unroll
    for (int kt = 0; kt < 16; kt++) {
      short8 b = *(const short8*)(bB + kt * 16);
      acc0 = MFMA(*(const short8*)(aB0 + kt * 512), b, acc0);
      acc1 = MFMA(*(const short8*)(aB1 + kt * 512), b, acc1);
    }
    store_act16(A2n + r32 * 264 + ctp * 32 + q * 16, acc0);
    store_act16(A2n + r32 * 264 + (ctp + 1) * 32 + q * 16, acc1);
  }
  __syncthreads();

  // ---- P3: wave w owns d0=w, d1=w+8; each A2 read feeds 2 MFMAs ----
  const int d0 = w, d1 = w + 8;
  const float* H32p = (const float*)(lds + LDS_H32);

  // e-GEMMs (A2W shared)
  f32x16 e0 = bias_init(wb3 + d0 * 32 + q * 16);
  f32x16 e1 = bias_init(wb3 + d1 * 32 + q * 16);
  {
    const unsigned short* aW0 = pw + OFF3W + (d0 * 16 * 64 + l) * 8;
    const unsigned short* aW1 = pw + OFF3W + (d1 * 16 * 64 + l) * 8;
    const unsigned short* bW = A2W + r32 * 264 + q * 8;
    #pragma unroll
    for (int kt = 0; kt < 16; kt++) {
      short8 b = *(const short8*)(bW + kt * 16);
      e0 = MFMA(*(const short8*)(aW0 + kt * 512), b, e0);
      e1 = MFMA(*(const short8*)(aW1 + kt * 512), b, e1);
    }
  }
  #pragma unroll
  for (int rr = 0; rr < 16; rr++) { e0[rr] = __expf(e0[rr]); e1[rr] = __expf(e1[rr]); }

  // h-GEMMs (A2H shared); wave 0 also accumulates h[.][32] from the same reads
  f32x16 h0 = bias_init(pwf + d0 * 32 + q * 16);
  f32x16 h1 = bias_init(pwf + d1 * 32 + q * 16);
  f32x16 a32;
  #pragma unroll
  for (int rr = 0; rr < 16; rr++) a32[rr] = 0.f;
  {
    const unsigned short* aH0 = pw + OFF3H + (d0 * 16 * 64 + l) * 8;
    const unsigned short* aH1 = pw + OFF3H + (d1 * 16 * 64 + l) * 8;
    const unsigned short* a32p = pw + OFFH32 + l * 8;
    const unsigned short* bH = A2H + r32 * 264 + q * 8;
    #pragma unroll
    for (int kt = 0; kt < 16; kt++) {
      short8 b = *(const short8*)(bH + kt * 16);
      h0 = MFMA(*(const short8*)(aH0 + kt * 512), b, h0);
      h1 = MFMA(*(const short8*)(aH1 + kt * 512), b, h1);
      if (w == 0) a32 = MFMA(*(const short8*)(a32p + kt * 512), b, a32);
    }
  }
  #pragma unroll
  for (int rr = 0; rr < 16; rr++) { h0[rr] = sp_eps(h0[rr]); h1[rr] = sp_eps(h1[rr]); }
  if (w == 0 && q == 0) {      // XA slot dead: H32 overlays it
    float* o = (float*)(lds + LDS_H32) + r32 * 16;
    const float* hb32 = pwf + 512;
    #pragma unroll
    for (int g = 0; g < 4; g++) {
      float4 v;
      v.x = sp_eps(a32[4 * g + 0] + hb32[4 * g + 0]);
      v.y = sp_eps(a32[4 * g + 1] + hb32[4 * g + 1]);
      v.z = sp_eps(a32[4 * g + 2] + hb32[4 * g + 2]);
      v.w = sp_eps(a32[4 * g + 3] + hb32[4 * g + 3]);
      *(float4*)(o + 4 * g) = v;
    }
  }
  __syncthreads();   // H32 visible before splines

  spline_store(e0, h0, d0, r32, q, H32p, x, y, r0);
  spline_store(e1, h1, d1, r32, q, H32p, x, y, r0);
}

extern "C" void kernel_launch(void* const* d_in, const int* in_sizes, int n_in,
                              void* d_out, int out_size, void* d_ws, size_t ws_size,
                              hipStream_t stream) {
  const float* x   = (const float*)d_in[0];
  const float* hW1 = (const float*)d_in[1];
  const float* hb1 = (const float*)d_in[2];
  const float* hW2 = (const float*)d_in[3];
  const float* hb2 = (const float*)d_in[4];
  const float* hW3 = (const float*)d_in[5];
  const float* hb3 = (const float*)d_in[6];
  const float* wW1 = (const float*)d_in[7];
  const float* wb1 = (const float*)d_in[8];
  const float* wW2 = (const float*)d_in[9];
  const float* wb2 = (const float*)d_in[10];
  const float* wW3 = (const float*)d_in[11];
  const float* wb3 = (const float*)d_in[12];
  unsigned short* pw = (unsigned short*)d_ws;

  pack_weights<<<801, 64, 0, stream>>>(hW1, wW1, hW2, wW2, hW3, wW3, hb3, pw);

  hipFuncSetAttribute((const void*)fused_kernel,
                      hipFuncAttributeMaxDynamicSharedMemorySize, LDS_TOTAL);
  fused_kernel<<<4096, 512, LDS_TOTAL, stream>>>(
      x, hb1, hb2, wb1, wb2, wb3, pw, (float*)d_out);
}

// Round 17
// 190.262 us; speedup vs baseline: 3.7678x; 1.0978x over previous
//
#include <hip/hip_runtime.h>
#include <cmath>

typedef short short8 __attribute__((ext_vector_type(8)));
typedef short short4v __attribute__((ext_vector_type(4)));
typedef float f32x16 __attribute__((ext_vector_type(16)));

#define EPSF 1.1920929e-07f

// ---------------- LDS layout (bytes), total 141312 (M=64, 1 block/CU) --------
#define LDS_A2W 0        // [64][264] ushort bf16
#define LDS_A2H 33792    // [64][264] ushort
#define LDS_A1W 67584    // [64][264] ushort (dead after L2)
#define LDS_A1H 101376   // [64][264] ushort (dead after L2)
#define LDS_XA  135168   // [64][16]  ushort (dead after L1)
#define LDS_EW  67584    // [64][288] ushort e = exp(raw_w)   (overlays A1W)
#define LDS_HH  104448   // [64][288] ushort h = softplus+EPS (overlays A1H+XA)
#define LDS_TOTAL 141312

// ---------------- packed weights (ushort elements) in d_ws ----------------
// B-frag for mfma_f32_32x32x16_bf16: lane l holds B[k=(l>>5)*8+e][n=l&31]
// tile = 512 ushort; storage order [nt][kt] (kt contiguous -> imm-offset folding)
#define OFF1H 0        // 8 tiles   (K=16: 1 kt x 8 nt)
#define OFF1W 4096
#define OFF2H 8192     // 128 tiles (8 nt x 16 kt)
#define OFF2W 73728
#define OFF3H 139264   // 272 tiles (17 nt x 16 kt, cols>=528 zero)
#define OFF3W 278528   // 256 tiles (16 nt x 16 kt)

__device__ __forceinline__ unsigned short f2bf(float f) {   // round-half-up
  union { float f; unsigned u; } v; v.f = f;
  return (unsigned short)((v.u + 0x8000u) >> 16);
}
__device__ __forceinline__ float bf2f(unsigned short h) {
  union { unsigned u; float f; } v; v.u = ((unsigned)h) << 16; return v.f;
}

__global__ void pack_weights(const float* __restrict__ hW1, const float* __restrict__ wW1,
                             const float* __restrict__ hW2, const float* __restrict__ wW2,
                             const float* __restrict__ hW3, const float* __restrict__ wW3,
                             unsigned short* __restrict__ out) {
  int tile = blockIdx.x, l = threadIdx.x;
  const float* src; unsigned short* dst; int NT, N, K, base;
  if (tile < 8)        { src = hW1; dst = out + OFF1H; NT = 8;  N = 256; K = 16;  base = tile; }
  else if (tile < 16)  { src = wW1; dst = out + OFF1W; NT = 8;  N = 256; K = 16;  base = tile - 8; }
  else if (tile < 144) { src = hW2; dst = out + OFF2H; NT = 8;  N = 256; K = 256; base = tile - 16; }
  else if (tile < 272) { src = wW2; dst = out + OFF2W; NT = 8;  N = 256; K = 256; base = tile - 144; }
  else if (tile < 544) { src = hW3; dst = out + OFF3H; NT = 17; N = 528; K = 256; base = tile - 272; }
  else                 { src = wW3; dst = out + OFF3W; NT = 16; N = 512; K = 256; base = tile - 544; }
  int nt = base % NT, kt = base / NT, KTT = K / 16;
  int n = nt * 32 + (l & 31);
  int k0 = kt * 16 + (l >> 5) * 8;
  short8 v;
  #pragma unroll
  for (int e = 0; e < 8; e++) {
    float f = (n < N && (k0 + e) < K) ? src[(k0 + e) * N + n] : 0.f;
    v[e] = (short)f2bf(f);
  }
  int idx = nt * KTT + kt;
  *(short8*)(dst + (idx * 64 + l) * 8) = v;
}

struct Acc2 { f32x16 a0, a1; };

// two 32x32 C-tiles (rows 0-31 and 32-63) sharing every B fragment.
template <int KT>
__device__ __forceinline__ Acc2 gemm_tile2(const unsigned short* __restrict__ A, int apitch,
                                           const unsigned short* __restrict__ pB, int ct,
                                           float init) {
  int l = threadIdx.x & 63;
  Acc2 r;
  #pragma unroll
  for (int i = 0; i < 16; i++) { r.a0[i] = init; r.a1[i] = init; }
  const unsigned short* aptr0 = A + (l & 31) * apitch + (l >> 5) * 8;
  const unsigned short* aptr1 = aptr0 + 32 * apitch;
  const unsigned short* bptr = pB + (ct * KT * 64 + l) * 8;
  if constexpr (KT == 1) {
    short8 b = *(const short8*)(bptr);
    short8 a0 = *(const short8*)(aptr0);
    short8 a1 = *(const short8*)(aptr1);
    r.a0 = __builtin_amdgcn_mfma_f32_32x32x16_bf16(a0, b, r.a0, 0, 0, 0);
    r.a1 = __builtin_amdgcn_mfma_f32_32x32x16_bf16(a1, b, r.a1, 0, 0, 0);
  } else {
    static_assert(KT % 4 == 0 || KT == 1, "KT groups of 4");
    short8 b0 = *(const short8*)(bptr + 0 * 512);
    short8 b1 = *(const short8*)(bptr + 1 * 512);
    short8 b2 = *(const short8*)(bptr + 2 * 512);
    short8 b3 = *(const short8*)(bptr + 3 * 512);
    #pragma unroll
    for (int g = 0; g < KT / 4; g++) {
      short8 n0, n1, n2, n3;
      if (g + 1 < KT / 4) {
        n0 = *(const short8*)(bptr + ((g + 1) * 4 + 0) * 512);
        n1 = *(const short8*)(bptr + ((g + 1) * 4 + 1) * 512);
        n2 = *(const short8*)(bptr + ((g + 1) * 4 + 2) * 512);
        n3 = *(const short8*)(bptr + ((g + 1) * 4 + 3) * 512);
      }
      #pragma unroll
      for (int j = 0; j < 4; j++) {
        int kt = g * 4 + j;
        short8 b = (j == 0) ? b0 : (j == 1) ? b1 : (j == 2) ? b2 : b3;
        short8 a0 = *(const short8*)(aptr0 + kt * 16);
        short8 a1 = *(const short8*)(aptr1 + kt * 16);
        r.a0 = __builtin_amdgcn_mfma_f32_32x32x16_bf16(a0, b, r.a0, 0, 0, 0);
        r.a1 = __builtin_amdgcn_mfma_f32_32x32x16_bf16(a1, b, r.a1, 0, 0, 0);
      }
      if (g + 1 < KT / 4) { b0 = n0; b1 = n1; b2 = n2; b3 = n3; }
    }
  }
  return r;
}

// C layout (m74/m101): col = lane&31, row = (reg&3) + 8*(reg>>2) + 4*(lane>>5)
__device__ __forceinline__ void epi_relu2(char* lds, int oOff, Acc2 a, int ct) {
  int l = threadIdx.x & 63;
  int col = ct * 32 + (l & 31);
  unsigned short* o = (unsigned short*)(lds + oOff) + col + 4 * (l >> 5) * 264;
  #pragma unroll
  for (int r = 0; r < 16; r++) {
    int row = (r & 3) + 8 * (r >> 2);
    o[row * 264] = f2bf(fmaxf(a.a0[r], 0.f));
    o[(row + 32) * 264] = f2bf(fmaxf(a.a1[r], 0.f));
  }
}

// __launch_bounds__ 2nd arg = min BLOCKS/CU on this toolchain (R8/R10 evidence).
// (1024,1): 16 waves = 4 waves/SIMD. Allocator self-caps at <=64 VGPR regardless
// (R11-R13) -- this config is the measured best (190.3 us).
__global__ __launch_bounds__(1024, 1) void fused_kernel(
    const float* __restrict__ x,
    const float* __restrict__ hb1, const float* __restrict__ hb2, const float* __restrict__ hb3,
    const float* __restrict__ wb1, const float* __restrict__ wb2, const float* __restrict__ wb3,
    const unsigned short* __restrict__ pw,
    float* __restrict__ y) {
  extern __shared__ char lds[];
  const int t = threadIdx.x;
  const int w = t >> 6, l = t & 63;
  const int r0 = blockIdx.x * 64;

  // phase 0: load x, emit y even cols, stage xA bf16 [64][16]
  if (t < 512) {
    int row = t >> 3, c4 = t & 7;
    float4 v = *(const float4*)(x + (r0 + row) * 32 + c4 * 4);
    y[(r0 + row) * 32 + c4 * 4] = v.x;
    y[(r0 + row) * 32 + c4 * 4 + 2] = v.z;
    unsigned short* xa = (unsigned short*)(lds + LDS_XA) + row * 16 + c4 * 2;
    xa[0] = f2bf(v.x); xa[1] = f2bf(v.z);
  }
  __syncthreads();

  const unsigned short* XA  = (const unsigned short*)(lds + LDS_XA);
  const unsigned short* A1W = (const unsigned short*)(lds + LDS_A1W);
  const unsigned short* A1H = (const unsigned short*)(lds + LDS_A1H);
  const unsigned short* A2W = (const unsigned short*)(lds + LDS_A2W);
  const unsigned short* A2H = (const unsigned short*)(lds + LDS_A2H);
  const int ct8 = w & 7;
  const int col8 = ct8 * 32 + (l & 31);

  // L1: waves 0-7 w-net, waves 8-15 h-net (each one col-tile, both row-tiles)
  if (w < 8) { epi_relu2(lds, LDS_A1W, gemm_tile2<1>(XA, 16, pw + OFF1W, ct8, wb1[col8]), ct8); }
  else       { epi_relu2(lds, LDS_A1H, gemm_tile2<1>(XA, 16, pw + OFF1H, ct8, hb1[col8]), ct8); }
  __syncthreads();
  // L2
  if (w < 8) { epi_relu2(lds, LDS_A2W, gemm_tile2<16>(A1W, 264, pw + OFF2W, ct8, wb2[col8]), ct8); }
  else       { epi_relu2(lds, LDS_A2H, gemm_tile2<16>(A1H, 264, pw + OFF2H, ct8, hb2[col8]), ct8); }
  __syncthreads();

  // ---- G3 + spline, two column-halves (H: d 0..7 then 8..15) ----
  #pragma unroll 1
  for (int H = 0; H < 2; H++) {
    for (int u = w; u < 17; u += 16) {
      if (u < 8) {
        int ctg = H * 8 + u;
        Acc2 a = gemm_tile2<16>(A2W, 264, pw + OFF3W, ctg, wb3[ctg * 32 + (l & 31)]);
        unsigned short* o = (unsigned short*)(lds + LDS_EW) + (ctg & 7) * 36 + (l & 31)
                            + 4 * (l >> 5) * 288;
        #pragma unroll
        for (int r = 0; r < 16; r++) {
          int row = (r & 3) + 8 * (r >> 2);
          o[row * 288] = f2bf(__expf(a.a0[r]));
          o[(row + 32) * 288] = f2bf(__expf(a.a1[r]));
        }
      } else {
        int ctg = (u - 8) + 8 * H;
        int c = ctg * 32 + (l & 31);
        float bv = (c < 528) ? hb3[c] : 0.f;
        Acc2 a = gemm_tile2<16>(A2H, 264, pw + OFF3H, ctg, bv);
        if (c >= 264 * H && c < 264 * (H + 1)) {
          unsigned d = ((unsigned)c * 993u) >> 15;  // c/33 for c<544
          int j = c - 33 * (int)d;
          unsigned short* o = (unsigned short*)(lds + LDS_HH) + ((int)d & 7) * 36 + j
                              + 4 * (l >> 5) * 288;
          #pragma unroll
          for (int r = 0; r < 16; r++) {
            int row = (r & 3) + 8 * (r >> 2);
            float v0 = a.a0[r];
            o[row * 288] = f2bf(fmaxf(v0, 0.f) + __logf(1.f + __expf(-fabsf(v0))) + EPSF);
            float v1 = a.a1[r];
            o[(row + 32) * 288] = f2bf(fmaxf(v1, 0.f) + __logf(1.f + __expf(-fabsf(v1))) + EPSF);
          }
        }
      }
    }
    __syncthreads();

    // ---- spline: pair (t, t^1) splits k-range; 512 (row,d) pairs ----
    {
      int p = t >> 1, half = t & 1;
      int row = p >> 3, dl = p & 7, dg = H * 8 + dl;
      const unsigned short* EWb = (const unsigned short*)(lds + LDS_EW) + row * 288 + dl * 36;
      const unsigned short* HHb = (const unsigned short*)(lds + LDS_HH) + row * 288 + dl * 36;
      const unsigned short* EWp = EWb + half * 16;
      const unsigned short* HHp = HHb + half * 16;
      float e[16], hh[17];
      #pragma unroll
      for (int i = 0; i < 4; i++) {
        short4v ev = *(const short4v*)(EWp + i * 4);
        short4v hv = *(const short4v*)(HHp + i * 4);
        #pragma unroll
        for (int jj = 0; jj < 4; jj++) {
          e[i * 4 + jj] = bf2f((unsigned short)ev[jj]);
          hh[i * 4 + jj] = bf2f((unsigned short)hv[jj]);
        }
      }
      hh[16] = bf2f(HHp[16]);
      float se = 0.f;
      #pragma unroll
      for (int k = 0; k < 16; k++) se += e[k];
      float so = __shfl_xor(se, 1);
      float s = se + so;
      float xbv = x[(r0 + row) * 32 + 2 * dg + 1];
      float xbs = xbv * s;
      float bl0 = half ? so : 0.f;
      int fnd = (xbs >= bl0) ? 1 : 0;
      float bl = bl0, cl2 = 0.f, sxl = bl0, scl2 = 0.f;
      int ki = 0;
      #pragma unroll
      for (int k = 0; k < 16; k++) {
        bool c = (xbs >= bl);
        ki   = c ? k   : ki;
        sxl  = c ? bl  : sxl;
        scl2 = c ? cl2 : scl2;
        cl2 += (hh[k] + hh[k + 1]) * e[k];
        bl  += e[k];
      }
      float cl2o = __shfl_xor(cl2, 1);
      float S2 = cl2 + cl2o;
      if (half) scl2 += cl2o;            // globalize half1's area prefix
      int   o_ki   = __shfl_xor(ki, 1);
      float o_sxl  = __shfl_xor(sxl, 1);
      float o_scl2 = __shfl_xor(scl2, 1);
      int   o_fnd  = __shfl_xor(fnd, 1);
      bool other = half ? (fnd == 0) : (o_fnd != 0);
      int   gki   = other ? o_ki   : ki;
      int   ghalf = other ? (half ^ 1) : half;
      float gsxl  = other ? o_sxl  : sxl;
      float gscl2 = other ? o_scl2 : scl2;
      int go = ghalf * 16 + gki;
      float sew = bf2f(EWb[go]);
      float shl = bf2f(HHb[go]);
      float shr = bf2f(HHb[go + 1]);
      float alpha = (xbs - gsxl) / (sew + EPSF);
      float yv = (gscl2 + (alpha * alpha * (shr - shl) + 2.f * alpha * shl) * sew) / S2;
      if (!half) y[(r0 + row) * 32 + 2 * dg + 1] = yv;
    }
    __syncthreads();
  }
}

extern "C" void kernel_launch(void* const* d_in, const int* in_sizes, int n_in,
                              void* d_out, int out_size, void* d_ws, size_t ws_size,
                              hipStream_t stream) {
  const float* x   = (const float*)d_in[0];
  const float* hW1 = (const float*)d_in[1];
  const float* hb1 = (const float*)d_in[2];
  const float* hW2 = (const float*)d_in[3];
  const float* hb2 = (const float*)d_in[4];
  const float* hW3 = (const float*)d_in[5];
  const float* hb3 = (const float*)d_in[6];
  const float* wW1 = (const float*)d_in[7];
  const float* wb1 = (const float*)d_in[8];
  const float* wW2 = (const float*)d_in[9];
  const float* wb2 = (const float*)d_in[10];
  const float* wW3 = (const float*)d_in[11];
  const float* wb3 = (const float*)d_in[12];
  unsigned short* pw = (unsigned short*)d_ws;

  pack_weights<<<800, 64, 0, stream>>>(hW1, wW1, hW2, wW2, hW3, wW3, pw);

  hipFuncSetAttribute((const void*)fused_kernel,
                      hipFuncAttributeMaxDynamicSharedMemorySize, LDS_TOTAL);
  fused_kernel<<<2048, 1024, LDS_TOTAL, stream>>>(
      x, hb1, hb2, hb3, wb1, wb2, wb3, pw, (float*)d_out);
}